// Round 11
// baseline (388.855 us; speedup 1.0000x reference)
//
#include <hip/hip_runtime.h>

#define N_NODES 100000
#define N_EDGES 500000
#define D 256
#define CAP 32          // bucket capacity per (node, relation); λ=5 ⇒ P(deg>32)≈1e-15
#define BROW 33         // bucket row stride in ints: [count | 32 ids] = 132B
#define BM 128          // rows per gemm block

typedef __bf16 bf16x8 __attribute__((ext_vector_type(8)));
typedef float  f32x4  __attribute__((ext_vector_type(4)));
typedef unsigned int u32x2 __attribute__((ext_vector_type(2)));

// ---- bf16 helpers (manual, RNE) -------------------------------------------
__device__ __forceinline__ unsigned short f2bf(float f) {
    unsigned int u = __float_as_uint(f);
    u += 0x7fffu + ((u >> 16) & 1u);
    return (unsigned short)(u >> 16);
}
__device__ __forceinline__ float bf2f(unsigned short b) {
    return __uint_as_float(((unsigned int)b) << 16);
}

// ---- async global->LDS, 16B per lane (dest = uniform base + lane*16) ------
__device__ __forceinline__ void glds16(const unsigned short* g, unsigned short* l) {
    __builtin_amdgcn_global_load_lds(
        (const __attribute__((address_space(1))) unsigned int*)g,
        (__attribute__((address_space(3))) unsigned int*)l,
        16, 0, 0);
}

// ---------------------------------------------------------------------------
// Prep kernel, WAVE-granular role interleave.
// Round-11 change: cnt merged INTO the bucket row — bc[node] = {count, 32
// ids}, stride 33 ints (132B). Each counter sits on its OWN cache line
// (old layout: 16 counters/64B line, ~160 atomics/line — candidate
// serialization hotspot). Zero extra memory vs cnt+bkt.
// Wt PRE-SWIZZLED k' = k ^ (((n>>1)&3)<<3) for linear-dest global_load_lds
// staging in the GEMM (m173 pattern).
// ---------------------------------------------------------------------------
#define PREP_BLOCKS 17188   // ceil(22*3125 waves / 4 per block)

__global__ __launch_bounds__(256) void prep_kernel(
    const float* __restrict__ x, unsigned short* __restrict__ xb,
    const float* __restrict__ Ws, const float* __restrict__ W1,
    const float* __restrict__ W2, unsigned short* __restrict__ Wt,
    const int* __restrict__ src1, const int* __restrict__ dst1,
    const int* __restrict__ src2, const int* __restrict__ dst2,
    int* __restrict__ bc1, int* __restrict__ bc2)
{
    const int wid  = blockIdx.x * 4 + (threadIdx.x >> 6);  // global wave id
    const int lane = threadIdx.x & 63;
    const int group = wid / 22;
    const int pos   = wid - group * 22;

    if (pos < 16) {
        // ---- convert role: x fp32 -> xb bf16, 8 elems/lane, contiguous ----
        int cw = group * 16 + pos;
        if (cw >= 50000) return;
        size_t base = (size_t)cw * 512;
        float4 a = *(const float4*)(x + base + lane * 4);
        float4 c = *(const float4*)(x + base + 256 + lane * 4);
        ushort4 oa, oc;
        oa.x = f2bf(a.x); oa.y = f2bf(a.y); oa.z = f2bf(a.z); oa.w = f2bf(a.w);
        oc.x = f2bf(c.x); oc.y = f2bf(c.y); oc.z = f2bf(c.z); oc.w = f2bf(c.w);
        *(ushort4*)(xb + base + lane * 4) = oa;
        *(ushort4*)(xb + base + 256 + lane * 4) = oc;
    } else if (pos < 21) {
        // ---- bucket role: 1 edge/lane; count word = bc[d*33] ----
        int bw = group * 5 + (pos - 16);
        int e = bw * 64 + lane;
        if (e >= 2 * N_EDGES) return;
        bool r2 = (e >= N_EDGES);
        const int* src = r2 ? src2 : src1;
        const int* dst = r2 ? dst2 : dst1;
        int* bc = r2 ? bc2 : bc1;
        int ei = r2 ? e - N_EDGES : e;
        int s = src[ei], d = dst[ei];
        int p = atomicAdd(&bc[(size_t)d * BROW], 1);
        if (p < CAP) bc[(size_t)d * BROW + 1 + p] = s;
    } else {
        // ---- W-prep role: Wt[n][k^swz] = bf16(scale_k * W[k%256][n]) ----
        int idx = group * 64 + lane;
        if (idx >= 3 * D * D) return;
        int k = idx >> 8;
        int n = idx & (D - 1);
        const float* W = (k < D) ? Ws : (k < 2 * D ? W1 : W2);
        float scale = (k < D) ? 1.1f : 1.0f;
        int dk = k ^ ((((n >> 1) & 3)) << 3);   // pre-swizzle 16B chunk slot
        Wt[(size_t)n * (3 * D) + dk] = f2bf(W[(size_t)(k & (D - 1)) * D + n] * scale);
    }
}

// ---------------------------------------------------------------------------
// Gather, one wave per NODE, both relations per task.
// Round-11: xa stores back to NONTEMPORAL (round-9 vs round-10 cross-round
// A/B: NT gather = 94.8us, plain = 99.0us; gemm indifferent — FETCH 78MB
// either way and gemm is not HBM-bound). Otherwise at fabric roofline
// (512MB random row reads + 102MB writes ≈ 6.2 TB/s) — frozen.
// ---------------------------------------------------------------------------
__global__ __launch_bounds__(256) void gather_kernel(
    const unsigned short* __restrict__ xb,
    const int* __restrict__ bc1, const int* __restrict__ bc2,
    unsigned short* __restrict__ xa1, unsigned short* __restrict__ xa2)
{
    long long gid = (long long)blockIdx.x * blockDim.x + threadIdx.x;
    int node = (int)(gid >> 6);
    int lane = (int)(gid & 63);
    if (node >= N_NODES) return;

    int c1 = bc1[(size_t)node * BROW]; if (c1 > CAP) c1 = CAP;
    int c2 = bc2[(size_t)node * BROW]; if (c2 > CAP) c2 = CAP;
    int sid1 = (lane < c1) ? bc1[(size_t)node * BROW + 1 + lane] : 0;
    int sid2 = (lane < c2) ? bc2[(size_t)node * BROW + 1 + lane] : 0;

    // 16 independent 512B row reads in flight (rel1 first, rel2 behind it).
    ushort4 v1[8], v2[8];
    #pragma unroll
    for (int t = 0; t < 8; ++t)
        v1[t] = *(const ushort4*)(xb + (size_t)__shfl(sid1, t) * D + lane * 4);
    #pragma unroll
    for (int t = 0; t < 8; ++t)
        v2[t] = *(const ushort4*)(xb + (size_t)__shfl(sid2, t) * D + lane * 4);

    // ---- rel1 fold (waits only on v1's 8 loads; v2 still in flight) ----
    {
        float a0 = 0.f, a1 = 0.f, a2 = 0.f, a3 = 0.f;
        #pragma unroll
        for (int t = 0; t < 8; ++t)
            if (t < c1) {   // wave-uniform predicate
                a0 += bf2f(v1[t].x); a1 += bf2f(v1[t].y);
                a2 += bf2f(v1[t].z); a3 += bf2f(v1[t].w);
            }
        for (int e = 8; e < c1; ++e) {   // tail P(deg>8)≈7%
            int s = __shfl(sid1, e);
            ushort4 t = *(const ushort4*)(xb + (size_t)s * D + lane * 4);
            a0 += bf2f(t.x); a1 += bf2f(t.y); a2 += bf2f(t.z); a3 += bf2f(t.w);
        }
        u32x2 o;
        o.x = (unsigned)f2bf(a0) | ((unsigned)f2bf(a1) << 16);
        o.y = (unsigned)f2bf(a2) | ((unsigned)f2bf(a3) << 16);
        __builtin_nontemporal_store(o, (u32x2*)(xa1 + (size_t)node * D + lane * 4));
    }

    // ---- rel2 fold ----
    {
        float a0 = 0.f, a1 = 0.f, a2 = 0.f, a3 = 0.f;
        #pragma unroll
        for (int t = 0; t < 8; ++t)
            if (t < c2) {
                a0 += bf2f(v2[t].x); a1 += bf2f(v2[t].y);
                a2 += bf2f(v2[t].z); a3 += bf2f(v2[t].w);
            }
        for (int e = 8; e < c2; ++e) {
            int s = __shfl(sid2, e);
            ushort4 t = *(const ushort4*)(xb + (size_t)s * D + lane * 4);
            a0 += bf2f(t.x); a1 += bf2f(t.y); a2 += bf2f(t.z); a3 += bf2f(t.w);
        }
        u32x2 o;
        o.x = (unsigned)f2bf(a0) | ((unsigned)f2bf(a1) << 16);
        o.y = (unsigned)f2bf(a2) | ((unsigned)f2bf(a3) << 16);
        __builtin_nontemporal_store(o, (u32x2*)(xa2 + (size_t)node * D + lane * 4));
    }
}

// ---------------------------------------------------------------------------
// MFMA GEMM, counted-vmcnt 3-deep pipeline (round-10 structure, kept).
// Round-11 add: T5 s_setprio(1/0) around the MFMA cluster — two co-resident
// blocks sit at different pipeline phases; prio lets MFMA-phase waves win
// issue arbitration over staging-phase waves.
// ---------------------------------------------------------------------------
__global__ __launch_bounds__(512, 4) void gemm_kernel(
    const unsigned short* __restrict__ xb,
    const unsigned short* __restrict__ xa1,
    const unsigned short* __restrict__ xa2,
    const unsigned short* __restrict__ Wt,   // [256 n][768 k] bf16, PRE-SWIZZLED
    const float* __restrict__ bias, float* __restrict__ out)
{
    __shared__ unsigned short Alds[3][BM * 32];     // 3 x 8 KB
    __shared__ unsigned short Blds[3][256 * 32];    // 3 x 16 KB

    const int tid  = threadIdx.x;
    const int lane = tid & 63;
    const int wave = tid >> 6;          // 0..7
    const int quad = lane >> 4;
    const int l15  = lane & 15;
    const int m0 = blockIdx.x * BM;
    const int wm = (wave >> 2) * 64;    // 2 m-waves x 4 n-waves of 64
    const int wn = (wave & 3) * 64;
    const int swz = (l15 >> 1) & 3;     // read-side chunk swizzle (row>>1)&3

    // glds geometry: each wave stages a 16-row slab; lane -> (row, chunk).
    const int gr   = lane >> 2;                 // row within slab 0..15
    const int gch  = lane & 3;                  // chunk slot 0..3
    const int gswz = (lane >> 3) & 3;           // (row>>1)&3 within slab
    int mRow = m0 + (wave << 4) + gr;           // A row this lane stages
    if (mRow >= N_NODES) mRow = N_NODES - 1;
    const size_t aRowOff = (size_t)mRow * D + ((gch ^ gswz) << 3);  // src XOR
    const unsigned short* bSrc0 = Wt + (size_t)((wave << 4) + gr) * (3 * D) + (gch << 3);
    const unsigned short* bSrc1 = bSrc0 + (size_t)128 * (3 * D);
    const unsigned short* Aseg[3] = {xb, xa1, xa2};

    f32x4 acc[4][4] = {};

    // Prologue: issue tiles 0 and 1 (6 loads in flight; no barrier yet —
    // iteration 0's vmcnt(6)+barrier covers the first consume).
    glds16(Aseg[0] + aRowOff,            &Alds[0][wave * 512]);
    glds16(bSrc0,                        &Blds[0][wave * 512]);
    glds16(bSrc1,                        &Blds[0][4096 + wave * 512]);
    glds16(Aseg[0] + aRowOff + 32,       &Alds[1][wave * 512]);
    glds16(bSrc0 + 32,                   &Blds[1][wave * 512]);
    glds16(bSrc1 + 32,                   &Blds[1][4096 + wave * 512]);

    for (int kt = 0; kt < 24; ++kt) {
        const int kpre = kt + 2;
        if (kpre < 24) {   // issue tile kt+2 (buffer (kt+2)%3 — last read at kt-1)
            const int b = kpre % 3;
            glds16(Aseg[kpre >> 3] + aRowOff + ((kpre & 7) * 32), &Alds[b][wave * 512]);
            glds16(bSrc0 + kpre * 32, &Blds[b][wave * 512]);
            glds16(bSrc1 + kpre * 32, &Blds[b][4096 + wave * 512]);
        }

        // Counted wait: my 3 loads for tile kt retired; rest stay in flight.
        if (kt < 22)       asm volatile("s_waitcnt vmcnt(6)" ::: "memory");
        else if (kt == 22) asm volatile("s_waitcnt vmcnt(3)" ::: "memory");
        else               asm volatile("s_waitcnt vmcnt(0)" ::: "memory");
        __builtin_amdgcn_s_barrier();      // all waves' tile-kt loads landed
        asm volatile("" ::: "memory");

        // MFMA on buffer kt%3 (B frags held across i)
        const unsigned short* Ab = &Alds[kt % 3][0];
        const unsigned short* Bb = &Blds[kt % 3][0];
        bf16x8 b0f = *(const bf16x8*)(Bb + (wn +  0 + l15) * 32 + ((quad ^ swz) * 8));
        bf16x8 b1f = *(const bf16x8*)(Bb + (wn + 16 + l15) * 32 + ((quad ^ swz) * 8));
        bf16x8 b2f = *(const bf16x8*)(Bb + (wn + 32 + l15) * 32 + ((quad ^ swz) * 8));
        bf16x8 b3f = *(const bf16x8*)(Bb + (wn + 48 + l15) * 32 + ((quad ^ swz) * 8));
        __builtin_amdgcn_s_setprio(1);
        #pragma unroll
        for (int i = 0; i < 4; ++i) {
            bf16x8 afi = *(const bf16x8*)(Ab + (wm + i * 16 + l15) * 32 + ((quad ^ swz) * 8));
            acc[i][0] = __builtin_amdgcn_mfma_f32_16x16x32_bf16(afi, b0f, acc[i][0], 0, 0, 0);
            acc[i][1] = __builtin_amdgcn_mfma_f32_16x16x32_bf16(afi, b1f, acc[i][1], 0, 0, 0);
            acc[i][2] = __builtin_amdgcn_mfma_f32_16x16x32_bf16(afi, b2f, acc[i][2], 0, 0, 0);
            acc[i][3] = __builtin_amdgcn_mfma_f32_16x16x32_bf16(afi, b3f, acc[i][3], 0, 0, 0);
        }
        __builtin_amdgcn_s_setprio(0);

        asm volatile("" ::: "memory");
        __builtin_amdgcn_s_barrier();      // all waves done reading buffer kt%3
        asm volatile("" ::: "memory");
    }

    // Epilogue: D layout col=lane&15, row=quad*4+reg (m89/m91 verified).
    #pragma unroll
    for (int j = 0; j < 4; ++j) {
        int col = wn + j * 16 + l15;
        float bj = bias[col];
        #pragma unroll
        for (int i = 0; i < 4; ++i) {
            int rb = m0 + wm + i * 16 + quad * 4;
            #pragma unroll
            for (int r = 0; r < 4; ++r) {
                int m = rb + r;
                if (m < N_NODES)
                    __builtin_nontemporal_store(
                        fmaxf(acc[i][j][r] + bj, 0.f),
                        out + (size_t)m * D + col);
            }
        }
    }
}

extern "C" void kernel_launch(void* const* d_in, const int* in_sizes, int n_in,
                              void* d_out, int out_size, void* d_ws, size_t ws_size,
                              hipStream_t stream) {
    const float* x    = (const float*)d_in[0];
    const float* Ws   = (const float*)d_in[1];
    const float* W1   = (const float*)d_in[2];
    const float* W2   = (const float*)d_in[3];
    const float* bias = (const float*)d_in[4];
    const int* src1   = (const int*)d_in[5];
    const int* dst1   = (const int*)d_in[6];
    const int* src2   = (const int*)d_in[7];
    const int* dst2   = (const int*)d_in[8];
    float* out = (float*)d_out;

    // Workspace layout (total 180.4 MB — unchanged):
    char* p = (char*)d_ws;
    unsigned short* xb  = (unsigned short*)p; p += (size_t)N_NODES * D * 2;  // 51.2 MB
    unsigned short* xa1 = (unsigned short*)p; p += (size_t)N_NODES * D * 2;  // 51.2 MB
    unsigned short* xa2 = (unsigned short*)p; p += (size_t)N_NODES * D * 2;  // 51.2 MB
    int* bc1 = (int*)p; p += (size_t)N_NODES * BROW * 4;                     // 13.2 MB
    int* bc2 = (int*)p; p += (size_t)N_NODES * BROW * 4;                     // 13.2 MB
    unsigned short* Wt = (unsigned short*)p;                                 // 0.39 MB

    (void)hipMemsetAsync(bc1, 0, (size_t)2 * N_NODES * BROW * 4, stream);

    prep_kernel<<<PREP_BLOCKS, 256, 0, stream>>>(
        x, xb, Ws, W1, W2, Wt, src1, dst1, src2, dst2, bc1, bc2);

    {   // gather-aggregate, one wave per node (both relations)
        long long total = (long long)N_NODES * 64;
        gather_kernel<<<(int)((total + 255) / 256), 256, 0, stream>>>(
            xb, bc1, bc2, xa1, xa2);
    }
    {   // MFMA GEMM + bias + relu, full-N blocks
        gemm_kernel<<<(N_NODES + BM - 1) / BM, 512, 0, stream>>>(
            xb, xa1, xa2, Wt, bias, out);
    }
}